// Round 16
// baseline (238.031 us; speedup 1.0000x reference)
//
#include <hip/hip_runtime.h>
#include <stdint.h>

#define BB 2
#define LL 2048
#define DD 1024
#define NHH 16
#define HSS 64

typedef __bf16 bf16x8 __attribute__((ext_vector_type(8)));
typedef float f32x4 __attribute__((ext_vector_type(4)));

// Load 8 consecutive elements as bf16x8, converting from fp32 if needed.
__device__ __forceinline__ bf16x8 load8(const float* p) {
  float4 f0 = *(const float4*)p;
  float4 f1 = *(const float4*)(p + 4);
  bf16x8 v;
  v[0] = (__bf16)f0.x; v[1] = (__bf16)f0.y; v[2] = (__bf16)f0.z; v[3] = (__bf16)f0.w;
  v[4] = (__bf16)f1.x; v[5] = (__bf16)f1.y; v[6] = (__bf16)f1.z; v[7] = (__bf16)f1.w;
  return v;
}
__device__ __forceinline__ bf16x8 load8(const __bf16* p) {
  return *(const bf16x8*)p;
}

// Async global->LDS DMA, 16B/lane. LDS dest WAVE-UNIFORM base; HW writes
// lane l at base + l*16 (m97-verified). Target LDS must be unpadded.
__device__ __forceinline__ void async_ld16(__bf16* lds_uniform_base,
                                           const __bf16* gptr_per_lane) {
  __builtin_amdgcn_global_load_lds(
      (const __attribute__((address_space(1))) void*)gptr_per_lane,
      (__attribute__((address_space(3))) void*)lds_uniform_base, 16, 0, 0);
}

// ---------------------------------------------------------------- prep (fused)
// z=0: Wqkv fp32 [1024][3072] -> WqkvT bf16 [3072][1024]   (3072 tiles)
// z=1: x fp32 -> xb bf16 elementwise (4.19M elems)          (2048 blocks)
// z=2: Er fp32 -> Erb bf16 elementwise (131072 elems)       (64 blocks)
__global__ void prep_k(const float* __restrict__ Wqkv, const float* __restrict__ x,
                       const float* __restrict__ Er, __bf16* __restrict__ WqkvT,
                       __bf16* __restrict__ xb, __bf16* __restrict__ Erb) {
  int tx = threadIdx.x, ty = threadIdx.y;
  int tid = ty * 32 + tx;
  if (blockIdx.z == 1) {
    if (blockIdx.x >= 2048) return;
    size_t off = ((size_t)blockIdx.x * 256 + tid) * 8;
    *(bf16x8*)&xb[off] = load8(&x[off]);
    return;
  }
  if (blockIdx.z == 2) {
    if (blockIdx.x >= 64) return;
    size_t off = ((size_t)blockIdx.x * 256 + tid) * 8;
    *(bf16x8*)&Erb[off] = load8(&Er[off]);
    return;
  }
  __shared__ __bf16 tile[32][33];
  int c0 = (blockIdx.x % 96) * 32, r0 = (blockIdx.x / 96) * 32;
#pragma unroll
  for (int i = ty; i < 32; i += 8)
    tile[i][tx] = (__bf16)Wqkv[(size_t)(r0 + i) * 3072 + c0 + tx];
  __syncthreads();
#pragma unroll
  for (int i = ty; i < 32; i += 8)
    WqkvT[(size_t)(c0 + i) * 1024 + r0 + tx] = tile[tx][i];
}

// ---------------------------------------------------------------- GEMM1
// qkv = xb[4096,1024] @ WqkvT[3072,1024]^T + bias.
// R26: DEPTH-2 DMA pipeline with COUNTED vmcnt (T4). 3-buffer rotation;
// tile k+2 issued at iter-k top; before the (raw) barrier only
// s_waitcnt vmcnt(4) -> tile k+1's 4 DMAs complete, tile k+2's stay in
// flight ACROSS the barrier (was: compiler vmcnt(0) drain exposed
// 200-900cyc L2 latency against ~240cyc of MFMA cover, every K-step).
// Race-safe: reads of a buffer are lgkm-consumed before the iter barrier;
// the overwrite for tile k+3 issues after it. Tail: clamped always-issue
// (dummy re-stage of tile31 into unread buffers) keeps the wait count
// uniform; full vmcnt(0)+syncthreads before the Vl-aliased epilogue.
// R25: XCD remap (768%8==0). R19: V^T via LDS transpose, coalesced.
__global__ __launch_bounds__(256) void gemm_qkv_k(
    const __bf16* __restrict__ A, const __bf16* __restrict__ Bt,
    const float* __restrict__ bias, __bf16* __restrict__ Qo,
    __bf16* __restrict__ Ko, __bf16* __restrict__ Vto) {
  const int K = 1024;
  __shared__ __align__(16) __bf16 smem[6 * 4096];  // As0..2 | Bs0..2 (8KB ea)
  __bf16* Vl = smem;                               // [64][136] epilogue alias
  int t = threadIdx.x;
  int wave = t >> 6, lane = t & 63, qd = lane >> 4, lr = lane & 15;
  int wg = (int)blockIdx.y * 24 + (int)blockIdx.x;
  wg = (wg & 7) * 96 + (wg >> 3);       // XCD-chunk remap (bijective, 768/8=96)
  int m0 = (wg / 24) * 128, n0 = (wg % 24) * 128;
  int wm = (wave >> 1) * 64, wn = (wave & 1) * 64;
  f32x4 acc[4][4] = {};
  int srow = lane >> 2, sch = (lane & 3) * 8;
  const __bf16* Ab[2];
  const __bf16* Bb[2];
#pragma unroll
  for (int c = 0; c < 2; c++) {
    Ab[c] = A + (size_t)(m0 + (wave * 2 + c) * 16 + srow) * K + sch;
    Bb[c] = Bt + (size_t)(n0 + (wave * 2 + c) * 16 + srow) * K + sch;
  }
  // prologue: stage tiles 0 and 1; wait tile0 (vmcnt(4) leaves tile1 in flight).
#pragma unroll
  for (int kt = 0; kt < 2; kt++) {
#pragma unroll
    for (int c = 0; c < 2; c++) {
      async_ld16(&smem[kt * 4096 + (wave * 2 + c) * 512], Ab[c] + kt * 32);
      async_ld16(&smem[(3 + kt) * 4096 + (wave * 2 + c) * 512], Bb[c] + kt * 32);
    }
  }
  asm volatile("s_waitcnt vmcnt(4)" ::: "memory");
  __builtin_amdgcn_s_barrier();
  __builtin_amdgcn_sched_barrier(0);

  for (int kt = 0; kt < 32; kt++) {
    int ktn = kt + 2;
    int bi = ktn % 3;
    int k0n = ((ktn < 32) ? ktn : 31) * 32;  // clamped (dummy re-stage at tail)
#pragma unroll
    for (int c = 0; c < 2; c++) {
      async_ld16(&smem[bi * 4096 + (wave * 2 + c) * 512], Ab[c] + k0n);
      async_ld16(&smem[(3 + bi) * 4096 + (wave * 2 + c) * 512], Bb[c] + k0n);
    }
    int rb = kt % 3;
    const __bf16* As = &smem[rb * 4096];
    const __bf16* Bs = &smem[(3 + rb) * 4096];
    bf16x8 af[4], bfr[4];
#pragma unroll
    for (int mt = 0; mt < 4; mt++)
      af[mt] = *(const bf16x8*)&As[(wm + mt * 16 + lr) * 32 + qd * 8];
#pragma unroll
    for (int nt = 0; nt < 4; nt++)
      bfr[nt] = *(const bf16x8*)&Bs[(wn + nt * 16 + lr) * 32 + qd * 8];
#pragma unroll
    for (int mt = 0; mt < 4; mt++)
#pragma unroll
      for (int nt = 0; nt < 4; nt++)
        acc[mt][nt] = __builtin_amdgcn_mfma_f32_16x16x32_bf16(af[mt], bfr[nt],
                                                              acc[mt][nt], 0, 0, 0);
    // tile kt+1 ready (4 newest = tile kt+2 may remain in flight)
    asm volatile("s_waitcnt vmcnt(4)" ::: "memory");
    __builtin_amdgcn_s_barrier();
    __builtin_amdgcn_sched_barrier(0);
  }
  // drain in-flight dummies before reusing smem as Vl; all reads done.
  asm volatile("s_waitcnt vmcnt(0)" ::: "memory");
  __syncthreads();

  // C/D: col = lane&15, row = quad*4 + reg
  float bvv[4];
#pragma unroll
  for (int nt = 0; nt < 4; nt++) bvv[nt] = bias[n0 + wn + nt * 16 + lr];

  if (n0 < 2 * DD) {
    // Q/K regions: row-major writes (blocks never straddle the Q/K boundary).
#pragma unroll
    for (int mt = 0; mt < 4; mt++)
#pragma unroll
      for (int nt = 0; nt < 4; nt++)
#pragma unroll
        for (int r = 0; r < 4; r++) {
          int row = m0 + wm + mt * 16 + qd * 4 + r;
          int col = n0 + wn + nt * 16 + lr;
          __bf16 bb = (__bf16)(acc[mt][nt][r] + bvv[nt]);
          int b = row >> 11, l = row & 2047;
          int h = (col >> 6) & 15, d = col & 63;
          if (col < DD) {
            Qo[(((size_t)(b * NHH + h)) * LL + l) * HSS + d] = bb;
          } else {
            Ko[(((size_t)(b * NHH + h)) * LL + l) * HSS + d] = bb;
          }
        }
  } else {
    // V region: LDS transpose then coalesced V^T row writes.
    int vb0 = n0 - 2 * DD;            // 128-aligned offset in V cols
    int bq = m0 >> 11, l0 = m0 & 2047;
    int vr = t >> 2, vc = (t & 3) * 8;
#pragma unroll
    for (int c = 0; c < 2; c++) {
      if ((wave & 1) == c) {
#pragma unroll
        for (int mt = 0; mt < 4; mt++)
#pragma unroll
          for (int nt = 0; nt < 4; nt++)
#pragma unroll
            for (int r = 0; r < 4; r++) {
              int vrow = nt * 16 + lr;                 // 0..63 (d within chunk)
              int ml = wm + mt * 16 + qd * 4 + r;      // 0..127 (m within tile)
              Vl[vrow * 136 + ml] = (__bf16)(acc[mt][nt][r] + bvv[nt]);
            }
      }
      __syncthreads();
      int h = (vb0 + c * 64) >> 6;   // chunk is 64-aligned -> single head
      __bf16* dst = Vto + (((size_t)(bq * NHH + h)) * HSS + vr) * LL + l0 + vc;
      const __bf16* src = &Vl[vr * 136 + vc];
#pragma unroll
      for (int u = 0; u < 4; u++)
        *(bf16x8*)(dst + u * 32) = *(const bf16x8*)(src + u * 32);
      __syncthreads();
    }
  }
}

// ---------------------------------------------------------------- GEMM2 (proj)
// out = Y[4096,1024](bf16) @ WprojT^T + bproj.
// R26: same depth-2 counted-vmcnt pipeline (3 DMAs/tile/wave -> vmcnt(3)).
// R25: XCD remap (512%8==0). Epilogue = R13 direct writes.
__global__ __launch_bounds__(256) void gemm_proj_k(
    const __bf16* __restrict__ A, const __bf16* __restrict__ Bt,
    const float* __restrict__ bias, float* __restrict__ out) {
  const int K = 1024, N = 1024;
  __shared__ __align__(16) __bf16 smem[3 * 4096 + 3 * 2048];  // As0..2|Bs0..2
  int t = threadIdx.x;
  int wave = t >> 6, lane = t & 63, qd = lane >> 4, lr = lane & 15;
  int wg = (int)blockIdx.y * 16 + (int)blockIdx.x;
  wg = (wg & 7) * 64 + (wg >> 3);       // XCD-chunk remap (bijective, 512/8=64)
  int m0 = (wg / 16) * 128, n0 = (wg % 16) * 64;
  int wm = (wave >> 1) * 64, wn = (wave & 1) * 32;
  f32x4 acc[4][2] = {};
  int srow = lane >> 2, sch = (lane & 3) * 8;
  const __bf16* Ab[2];
  const __bf16* Bb;
#pragma unroll
  for (int c = 0; c < 2; c++)
    Ab[c] = A + (size_t)(m0 + (wave * 2 + c) * 16 + srow) * K + sch;
  Bb = Bt + (size_t)(n0 + wave * 16 + srow) * K + sch;

#pragma unroll
  for (int kt = 0; kt < 2; kt++) {
#pragma unroll
    for (int c = 0; c < 2; c++)
      async_ld16(&smem[kt * 4096 + (wave * 2 + c) * 512], Ab[c] + kt * 32);
    async_ld16(&smem[3 * 4096 + kt * 2048 + wave * 512], Bb + kt * 32);
  }
  asm volatile("s_waitcnt vmcnt(3)" ::: "memory");
  __builtin_amdgcn_s_barrier();
  __builtin_amdgcn_sched_barrier(0);

  for (int kt = 0; kt < 32; kt++) {
    int ktn = kt + 2;
    int bi = ktn % 3;
    int k0n = ((ktn < 32) ? ktn : 31) * 32;  // clamped tail
#pragma unroll
    for (int c = 0; c < 2; c++)
      async_ld16(&smem[bi * 4096 + (wave * 2 + c) * 512], Ab[c] + k0n);
    async_ld16(&smem[3 * 4096 + bi * 2048 + wave * 512], Bb + k0n);
    int rb = kt % 3;
    const __bf16* As = &smem[rb * 4096];
    const __bf16* Bs = &smem[3 * 4096 + rb * 2048];
    bf16x8 af[4], bfr[2];
#pragma unroll
    for (int mt = 0; mt < 4; mt++)
      af[mt] = *(const bf16x8*)&As[(wm + mt * 16 + lr) * 32 + qd * 8];
#pragma unroll
    for (int nt = 0; nt < 2; nt++)
      bfr[nt] = *(const bf16x8*)&Bs[(wn + nt * 16 + lr) * 32 + qd * 8];
#pragma unroll
    for (int mt = 0; mt < 4; mt++)
#pragma unroll
      for (int nt = 0; nt < 2; nt++)
        acc[mt][nt] = __builtin_amdgcn_mfma_f32_16x16x32_bf16(af[mt], bfr[nt],
                                                              acc[mt][nt], 0, 0, 0);
    asm volatile("s_waitcnt vmcnt(3)" ::: "memory");
    __builtin_amdgcn_s_barrier();
    __builtin_amdgcn_sched_barrier(0);
  }
  float bvv[2];
#pragma unroll
  for (int nt = 0; nt < 2; nt++) bvv[nt] = bias[n0 + wn + nt * 16 + lr];
#pragma unroll
  for (int mt = 0; mt < 4; mt++)
#pragma unroll
    for (int nt = 0; nt < 2; nt++)
#pragma unroll
      for (int r = 0; r < 4; r++) {
        int row = m0 + wm + mt * 16 + qd * 4 + r;
        int col = n0 + wn + nt * 16 + lr;
        out[(size_t)row * N + col] = acc[mt][nt][r] + bvv[nt];
      }
}

// ---------------------------------------------------------------- flash attn
// SPLIT-K over j (z=2 halves): unnormalized softmax partials are ADDITIVE:
// Y = (O0+O1)/(l0+l1). Grid (bh=32, tile=32 heavy-first, half=2) = 2048.
// Loop = R10 verbatim (106us floor, 6 falsified attack angles).
__global__ __launch_bounds__(256, 3) void flash_k(
    const __bf16* __restrict__ Qg, const __bf16* __restrict__ Kg,
    const __bf16* __restrict__ Vtg, const __bf16* __restrict__ Erb,
    __bf16* __restrict__ Po0, __bf16* __restrict__ Po1,
    float* __restrict__ Lp0, float* __restrict__ Lp1) {
  __shared__ __align__(16) __bf16 Kbuf[2][64 * 64];   // [j][d], swizzled
  __shared__ __align__(16) __bf16 Vbuf[2][64 * 64];   // [d][j], swizzled
  __shared__ __align__(16) __bf16 Pball[4][16 * 64];  // per-wave P, swizzled

  int bh = blockIdx.x;
  int tile = 31 - (int)blockIdx.y;  // heavy tiles dispatch first
  int i0 = tile * 64;
  int niter = tile + 1;
  int mid = (niter + 1) >> 1;
  int it0 = (blockIdx.z == 0) ? 0 : mid;
  int it1 = (blockIdx.z == 0) ? mid : niter;
  const __bf16* Qh = Qg + (size_t)bh * LL * HSS;
  const __bf16* Kh = Kg + (size_t)bh * LL * HSS;
  const __bf16* Vth = Vtg + (size_t)bh * HSS * LL;
  int b = bh >> 4, h = bh & 15;
  int t = threadIdx.x, wave = t >> 6, lane = t & 63, qd = lane >> 4, lr = lane & 15;
  __bf16* Pb = &Pball[wave][0];
  int cbase = 48 - wave * 16;

  // 0.125 * log2(e): fold softmax scale + base-e->base-2 into one fp32 mul.
  const float SC = 0.18033688011112042f;

  // DMA source addressing (per-lane, inverse-swizzled):
  int lrow = lane >> 3;                  // 0..7 row within 8-row chunk
  int lcol = ((lane & 7) ^ lrow) * 8;    // swizzled col chunk (elems)
  const __bf16* KsrcB[2];
  const __bf16* VsrcB[2];
#pragma unroll
  for (int c = 0; c < 2; c++) {
    int q = wave * 2 + c;                // chunk 0..7 (8 rows each)
    KsrcB[c] = Kh + (size_t)(q * 8 + lrow) * HSS + lcol;
    VsrcB[c] = Vth + (size_t)(q * 8 + lrow) * LL + lcol;
  }

  // swizzled read col offsets (elems): chunk qd -> qd^(lr&7); qd+4 likewise
  int swA = (qd ^ (lr & 7)) * 8;
  int swB = ((qd + 4) ^ (lr & 7)) * 8;

  // slim per-r invariants (bases only; per-r offsets are unroll constants)
  int hi8 = lr >> 3;
  int ib0 = 15 - qd * 4 + lr;        // bpermute base for r=0
  int pb0 = qd * 256 + (lr & 7);     // P write base (row tr=qd*4+r at +r*64)
  int px0 = (qd & 1) * 4;            // P chunk-xor for r=0
  int rowb = i0 + wave * 16 + qd * 4;  // global row base

  bf16x8 aq[2];
  {
    const __bf16* qrow = Qh + (size_t)(i0 + wave * 16 + lr) * HSS + qd * 8;
    aq[0] = *(const bf16x8*)qrow;
    aq[1] = *(const bf16x8*)(qrow + 32);
  }
  f32x4 oacc[4] = {};   // O d-tiles
  float lsum[4] = {};   // row sums (VALU)

  // prologue: DMA tile it0 into buffer 0, then barrier (drains vmcnt).
  int cur = 0;
  if (it0 < it1) {
    int j0 = it0 * 64;
#pragma unroll
    for (int c = 0; c < 2; c++) {
      async_ld16(&Kbuf[0][(wave * 2 + c) * 512], KsrcB[c] + (size_t)j0 * HSS);
      async_ld16(&Vbuf[0][(wave * 2 + c) * 512], VsrcB[c] + j0);
    }
  }
  __syncthreads();

  for (int it = it0; it < it1; ++it) {
    int j0 = it * 64;

    // issue DMA for NEXT tile into the other buffer; completes before the
    // trailing barrier's vmcnt drain (a full iteration of compute away).
    if (it + 1 < it1) {
      int jn = (it + 1) * 64;
#pragma unroll
      for (int c = 0; c < 2; c++) {
        async_ld16(&Kbuf[cur ^ 1][(wave * 2 + c) * 512], KsrcB[c] + (size_t)jn * HSS);
        async_ld16(&Vbuf[cur ^ 1][(wave * 2 + c) * 512], VsrcB[c] + jn);
      }
    }

    // Er rows for this iter's 80-col window (clamped rows feed masked cols).
    int ebase = LL - 64 - i0 + j0 + cbase + lr;
    int e[5];
#pragma unroll
    for (int ct = 0; ct < 5; ct++) {
      int v = ebase + ct * 16;
      e[ct] = (v < LL) ? v : (LL - 1);
    }
    // kc=0 Er batch issued BEFORE QK: QK MFMAs + ds_reads hide L2 latency.
    bf16x8 ef0[5];
#pragma unroll
    for (int ct = 0; ct < 5; ct++)
      ef0[ct] = *(const bf16x8*)&Erb[(size_t)e[ct] * HSS + qd * 8];

    const __bf16* Kb = &Kbuf[cur][0];
    const __bf16* Vb = &Vbuf[cur][0];

    // QK^T: 4 col-tiles x 2 k-chunks (swizzled LDS reads)
    f32x4 sacc[4] = {};
    __builtin_amdgcn_s_setprio(1);
#pragma unroll
    for (int ct = 0; ct < 4; ct++) {
      bf16x8 bk0 = *(const bf16x8*)&Kb[(ct * 16 + lr) * 64 + swA];
      bf16x8 bk1 = *(const bf16x8*)&Kb[(ct * 16 + lr) * 64 + swB];
      sacc[ct] = __builtin_amdgcn_mfma_f32_16x16x32_bf16(aq[0], bk0, sacc[ct], 0, 0, 0);
      sacc[ct] = __builtin_amdgcn_mfma_f32_16x16x32_bf16(aq[1], bk1, sacc[ct], 0, 0, 0);
    }
    __builtin_amdgcn_s_setprio(0);

    // kc=1 Er batch issued here, consumed after the kc=0 rel MFMAs.
    bf16x8 ef1[5];
#pragma unroll
    for (int ct = 0; ct < 5; ct++)
      ef1[ct] = *(const bf16x8*)&Erb[(size_t)e[ct] * HSS + 32 + qd * 8];

    // rel: 5 col-tiles over the 80-col window, B-frags from registers
    f32x4 racc[5] = {};
    __builtin_amdgcn_s_setprio(1);
#pragma unroll
    for (int ct = 0; ct < 5; ct++)
      racc[ct] = __builtin_amdgcn_mfma_f32_16x16x32_bf16(aq[0], ef0[ct], racc[ct], 0, 0, 0);
#pragma unroll
    for (int ct = 0; ct < 5; ct++)
      racc[ct] = __builtin_amdgcn_mfma_f32_16x16x32_bf16(aq[1], ef1[ct], racc[ct], 0, 0, 0);
    __builtin_amdgcn_s_setprio(0);

    // Rel diagonal gather via bpermute, p = exp2(SC*s), l on VALU.
    int dib = rowb - j0;
#pragma unroll
    for (int r = 0; r < 4; r++) {
      int bse = ib0 - r;
      int hi = bse >> 4;
      int idx = (qd * 16 + (bse & 15)) << 2;
      float sh[5];
#pragma unroll
      for (int ct = 0; ct < 5; ct++)
        sh[ct] = __int_as_float(
            __builtin_amdgcn_ds_bpermute(idx, __float_as_int(racc[ct][r])));
      int di = dib + r;
#pragma unroll
      for (int ct2 = 0; ct2 < 4; ct2++) {
        float rel = hi ? sh[ct2 + 1] : sh[ct2];
        float p = __builtin_exp2f((sacc[ct2][r] + rel) * SC);
        p = (ct2 * 16 + lr <= di) ? p : 0.f;
        __bf16 pb = (__bf16)p;
        lsum[r] += (float)pb;  // bf16-rounded to match PV numerics
        Pb[pb0 + r * 64 + (((2 * ct2 + hi8) ^ (px0 + r)) << 3)] = pb;
      }
    }

    // O += P V (dt 0..3, swizzled LDS V-frags; P read swizzled like K/V)
    bf16x8 ap0 = *(const bf16x8*)&Pb[lr * 64 + swA];
    bf16x8 ap1 = *(const bf16x8*)&Pb[lr * 64 + swB];
    __builtin_amdgcn_s_setprio(1);
#pragma unroll
    for (int dt = 0; dt < 4; dt++) {
      bf16x8 bv0 = *(const bf16x8*)&Vb[(dt * 16 + lr) * 64 + swA];
      bf16x8 bv1 = *(const bf16x8*)&Vb[(dt * 16 + lr) * 64 + swB];
      oacc[dt] = __builtin_amdgcn_mfma_f32_16x16x32_bf16(ap0, bv0, oacc[dt], 0, 0, 0);
      oacc[dt] = __builtin_amdgcn_mfma_f32_16x16x32_bf16(ap1, bv1, oacc[dt], 0, 0, 0);
    }
    __builtin_amdgcn_s_setprio(0);

    __syncthreads();  // next buffer ready (vmcnt drained), P safe to rewrite
    cur ^= 1;
  }

  // l: reduce across the 16 lanes of each quad-group (cols of the row).
#pragma unroll
  for (int r = 0; r < 4; r++) {
#pragma unroll
    for (int m = 1; m < 16; m <<= 1)
      lsum[r] += __shfl_xor(lsum[r], m, 64);
  }

  // epilogue: write UNNORMALIZED partial O (bf16) and partial l (fp32).
  __bf16* Po = (blockIdx.z == 0) ? Po0 : Po1;
  float* Lp = (blockIdx.z == 0) ? Lp0 : Lp1;
#pragma unroll
  for (int r = 0; r < 4; r++) {
    int l = i0 + wave * 16 + qd * 4 + r;
    if (lr == 0) Lp[(size_t)bh * LL + l] = lsum[r];
#pragma unroll
    for (int dt = 0; dt < 4; dt++) {
      int d = dt * 16 + lr;
      Po[((size_t)(b * LL) + l) * DD + h * HSS + d] = (__bf16)oacc[dt][r];
    }
  }
}

// ------------------------------------------------- combine + tconv (fused)
// id < 2048:  Y = (Po0 + Po1) / (Lp0 + Lp1)  elementwise (256 thr/blk x8).
// id >= 2048: Wproj fp32 [1024][1024] -> WprojT bf16 (32x32 tiles, 1024 blk).
__global__ void ct_k(const __bf16* __restrict__ Po0,
                     const __bf16* __restrict__ Po1,
                     const float* __restrict__ Lp0,
                     const float* __restrict__ Lp1,
                     __bf16* __restrict__ Y,
                     const float* __restrict__ Wproj,
                     __bf16* __restrict__ WprojT) {
  int id = blockIdx.x;
  if (id < 2048) {
    size_t f = ((size_t)id * 256 + threadIdx.x) * 8;
    int dfull = (int)(f & 1023);
    int h = dfull >> 6;
    int l = (int)((f >> 10) & 2047);
    int b = (int)(f >> 21);
    size_t lidx = ((size_t)(b * NHH + h)) * LL + l;
    float linv = 1.f / (Lp0[lidx] + Lp1[lidx]);
    bf16x8 a = *(const bf16x8*)&Po0[f];
    bf16x8 c = *(const bf16x8*)&Po1[f];
    bf16x8 o;
#pragma unroll
    for (int q = 0; q < 8; q++)
      o[q] = (__bf16)(((float)a[q] + (float)c[q]) * linv);
    *(bf16x8*)&Y[f] = o;
    return;
  }
  __shared__ __bf16 tile[32][33];
  int q = id - 2048;
  int c0 = (q & 31) * 32, r0 = (q >> 5) * 32;
  int tx = threadIdx.x & 31, ty = threadIdx.x >> 5;
#pragma unroll
  for (int i = ty; i < 32; i += 8)
    tile[i][tx] = (__bf16)Wproj[(size_t)(r0 + i) * 1024 + c0 + tx];
  __syncthreads();
#pragma unroll
  for (int i = ty; i < 32; i += 8)
    WprojT[(size_t)(c0 + i) * 1024 + r0 + tx] = tile[tx][i];
}

// ---------------------------------------------------------------- launch
extern "C" void kernel_launch(void* const* d_in, const int* in_sizes, int n_in,
                              void* d_out, int out_size, void* d_ws, size_t ws_size,
                              hipStream_t stream) {
  // Reference dtypes: ALL inputs fp32, output fp32 (confirmed round 4).
  const float* x = (const float*)d_in[0];
  const float* Wqkv = (const float*)d_in[1];
  const float* bqkv = (const float*)d_in[2];
  const float* Wproj = (const float*)d_in[3];
  const float* bproj = (const float*)d_in[4];
  const float* Er = (const float*)d_in[5];
  float* out = (float*)d_out;

  if (ws_size < 4u * 8388608u) return;  // 32 MiB used, confirmed present

  uint8_t* w = (uint8_t*)d_ws;
  __bf16* Q = (__bf16*)w;  w += (size_t)BB * NHH * LL * HSS * 2;
  __bf16* Kt = (__bf16*)w; w += (size_t)BB * NHH * LL * HSS * 2;
  __bf16* Vt = (__bf16*)w; w += (size_t)BB * NHH * LL * HSS * 2;
  __bf16* Y = (__bf16*)w;  w += (size_t)BB * LL * DD * 2;

  // d_out scratch overlay (16.78 MB):
  //   Pre-GEMM1: WqkvT 6.29 MB @0, xb 8.39 MB @6.29M (both dead after GEMM1).
  //   During flash: Po1 8.39 MB @0, Lp0 0.26 MB @8.39M, Lp1 0.26 MB @8.65M,
  //   Erb 0.26 MB @14.68M (live through flash; no overlap).
  //   gemm_proj overwrites all of d_out last.
  __bf16* WqkvT = (__bf16*)d_out;
  __bf16* xb = (__bf16*)((uint8_t*)d_out + (size_t)3072 * 1024 * 2);
  __bf16* Erb = (__bf16*)((uint8_t*)d_out + (size_t)3072 * 1024 * 2 + (size_t)4096 * 1024 * 2);
  __bf16* Po1 = (__bf16*)d_out;
  float* Lp0 = (float*)((uint8_t*)d_out + (size_t)BB * LL * DD * 2);
  float* Lp1 = (float*)((uint8_t*)d_out + (size_t)BB * LL * DD * 2 + (size_t)BB * NHH * LL * 4);
  __bf16* Po0 = Y;       // ct_k reads+rewrites Y in place (same-thread RAW)
  __bf16* WprojT = Q;    // written after flash (Q dead by then)

  prep_k<<<dim3(3072, 1, 3), dim3(32, 8), 0, stream>>>(Wqkv, x, Er, WqkvT, xb, Erb);
  gemm_qkv_k<<<dim3(3072 / 128, 4096 / 128), 256, 0, stream>>>(
      xb, WqkvT, bqkv, Q, Kt, Vt);
  flash_k<<<dim3(BB * NHH, 32, 2), 256, 0, stream>>>(
      Q, Kt, Vt, Erb, Po0, Po1, Lp0, Lp1);
  ct_k<<<dim3(3072), 256, 0, stream>>>(Po0, Po1, Lp0, Lp1, Y, Wproj, WprojT);
  gemm_proj_k<<<dim3(1024 / 64, 4096 / 128), 256, 0, stream>>>(Y, WprojT, bproj, out);
}

// Round 17
// 235.116 us; speedup vs baseline: 1.0124x; 1.0124x over previous
//
#include <hip/hip_runtime.h>
#include <stdint.h>

#define BB 2
#define LL 2048
#define DD 1024
#define NHH 16
#define HSS 64

typedef __bf16 bf16x8 __attribute__((ext_vector_type(8)));
typedef float f32x4 __attribute__((ext_vector_type(4)));

// Load 8 consecutive elements as bf16x8, converting from fp32 if needed.
__device__ __forceinline__ bf16x8 load8(const float* p) {
  float4 f0 = *(const float4*)p;
  float4 f1 = *(const float4*)(p + 4);
  bf16x8 v;
  v[0] = (__bf16)f0.x; v[1] = (__bf16)f0.y; v[2] = (__bf16)f0.z; v[3] = (__bf16)f0.w;
  v[4] = (__bf16)f1.x; v[5] = (__bf16)f1.y; v[6] = (__bf16)f1.z; v[7] = (__bf16)f1.w;
  return v;
}
__device__ __forceinline__ bf16x8 load8(const __bf16* p) {
  return *(const bf16x8*)p;
}

// Async global->LDS DMA, 16B/lane. LDS dest WAVE-UNIFORM base; HW writes
// lane l at base + l*16 (m97-verified). Target LDS must be unpadded.
__device__ __forceinline__ void async_ld16(__bf16* lds_uniform_base,
                                           const __bf16* gptr_per_lane) {
  __builtin_amdgcn_global_load_lds(
      (const __attribute__((address_space(1))) void*)gptr_per_lane,
      (__attribute__((address_space(3))) void*)lds_uniform_base, 16, 0, 0);
}

// ---------------------------------------------------------------- prep (fused)
// z=0: Wqkv fp32 [1024][3072] -> WqkvT bf16 [3072][1024]   (3072 tiles)
// z=1: x fp32 -> xb bf16 elementwise (4.19M elems)          (2048 blocks)
// z=2: Er fp32 -> Erb bf16 elementwise (131072 elems)       (64 blocks)
__global__ void prep_k(const float* __restrict__ Wqkv, const float* __restrict__ x,
                       const float* __restrict__ Er, __bf16* __restrict__ WqkvT,
                       __bf16* __restrict__ xb, __bf16* __restrict__ Erb) {
  int tx = threadIdx.x, ty = threadIdx.y;
  int tid = ty * 32 + tx;
  if (blockIdx.z == 1) {
    if (blockIdx.x >= 2048) return;
    size_t off = ((size_t)blockIdx.x * 256 + tid) * 8;
    *(bf16x8*)&xb[off] = load8(&x[off]);
    return;
  }
  if (blockIdx.z == 2) {
    if (blockIdx.x >= 64) return;
    size_t off = ((size_t)blockIdx.x * 256 + tid) * 8;
    *(bf16x8*)&Erb[off] = load8(&Er[off]);
    return;
  }
  __shared__ __bf16 tile[32][33];
  int c0 = (blockIdx.x % 96) * 32, r0 = (blockIdx.x / 96) * 32;
#pragma unroll
  for (int i = ty; i < 32; i += 8)
    tile[i][tx] = (__bf16)Wqkv[(size_t)(r0 + i) * 3072 + c0 + tx];
  __syncthreads();
#pragma unroll
  for (int i = ty; i < 32; i += 8)
    WqkvT[(size_t)(c0 + i) * 1024 + r0 + tx] = tile[tx][i];
}

// ---------------------------------------------------------------- GEMM1
// qkv = xb[4096,1024] @ WqkvT[3072,1024]^T + bias.
// R23: single-barrier DMA double-buffer K-loop (flash-proven pattern).
// R25: XCD-aware bijective block remap (T1; 768%8==0).
// R27 (final): R26's depth-2 counted-vmcnt was NEUTRAL -> GEMM barrier
// drain is not the bottleneck (matches catalog regime-gate: T4 needs the
// full 8-phase structure). Locked at the best-measured R15 form.
// R19: V-region blocks write V^T rows COALESCED via LDS transpose.
__global__ __launch_bounds__(256) void gemm_qkv_k(
    const __bf16* __restrict__ A, const __bf16* __restrict__ Bt,
    const float* __restrict__ bias, __bf16* __restrict__ Qo,
    __bf16* __restrict__ Ko, __bf16* __restrict__ Vto) {
  const int K = 1024;
  __shared__ __align__(16) __bf16 smem[4 * 4096];  // As0|As1|Bs0|Bs1 (8KB ea)
  __bf16* Vl = smem;                               // [64][136] epilogue alias
  int t = threadIdx.x;
  int wave = t >> 6, lane = t & 63, qd = lane >> 4, lr = lane & 15;
  int wg = (int)blockIdx.y * 24 + (int)blockIdx.x;
  wg = (wg & 7) * 96 + (wg >> 3);       // XCD-chunk remap (bijective, 768/8=96)
  int m0 = (wg / 24) * 128, n0 = (wg % 24) * 128;
  int wm = (wave >> 1) * 64, wn = (wave & 1) * 64;
  f32x4 acc[4][4] = {};
  int srow = lane >> 2, sch = (lane & 3) * 8;
  const __bf16* Ab[2];
  const __bf16* Bb[2];
#pragma unroll
  for (int c = 0; c < 2; c++) {
    Ab[c] = A + (size_t)(m0 + (wave * 2 + c) * 16 + srow) * K + sch;
    Bb[c] = Bt + (size_t)(n0 + (wave * 2 + c) * 16 + srow) * K + sch;
  }
  // prologue: stage k0=0 into buffer 0, drain, enter loop.
#pragma unroll
  for (int c = 0; c < 2; c++) {
    async_ld16(&smem[0 * 4096 + (wave * 2 + c) * 512], Ab[c]);
    async_ld16(&smem[2 * 4096 + (wave * 2 + c) * 512], Bb[c]);
  }
  __syncthreads();
  int cur = 0;
  for (int k0 = 0; k0 < K; k0 += 32) {
    if (k0 + 32 < K) {
#pragma unroll
      for (int c = 0; c < 2; c++) {
        async_ld16(&smem[(cur ^ 1) * 4096 + (wave * 2 + c) * 512], Ab[c] + k0 + 32);
        async_ld16(&smem[(2 + (cur ^ 1)) * 4096 + (wave * 2 + c) * 512], Bb[c] + k0 + 32);
      }
    }
    const __bf16* As = &smem[cur * 4096];
    const __bf16* Bs = &smem[(2 + cur) * 4096];
    bf16x8 af[4], bfr[4];
#pragma unroll
    for (int mt = 0; mt < 4; mt++)
      af[mt] = *(const bf16x8*)&As[(wm + mt * 16 + lr) * 32 + qd * 8];
#pragma unroll
    for (int nt = 0; nt < 4; nt++)
      bfr[nt] = *(const bf16x8*)&Bs[(wn + nt * 16 + lr) * 32 + qd * 8];
#pragma unroll
    for (int mt = 0; mt < 4; mt++)
#pragma unroll
      for (int nt = 0; nt < 4; nt++)
        acc[mt][nt] = __builtin_amdgcn_mfma_f32_16x16x32_bf16(af[mt], bfr[nt],
                                                              acc[mt][nt], 0, 0, 0);
    __syncthreads();  // prefetched buffer ready; current buffer reusable
    cur ^= 1;
  }
  // C/D: col = lane&15, row = quad*4 + reg
  float bvv[4];
#pragma unroll
  for (int nt = 0; nt < 4; nt++) bvv[nt] = bias[n0 + wn + nt * 16 + lr];

  if (n0 < 2 * DD) {
    // Q/K regions: row-major writes (blocks never straddle the Q/K boundary).
#pragma unroll
    for (int mt = 0; mt < 4; mt++)
#pragma unroll
      for (int nt = 0; nt < 4; nt++)
#pragma unroll
        for (int r = 0; r < 4; r++) {
          int row = m0 + wm + mt * 16 + qd * 4 + r;
          int col = n0 + wn + nt * 16 + lr;
          __bf16 bb = (__bf16)(acc[mt][nt][r] + bvv[nt]);
          int b = row >> 11, l = row & 2047;
          int h = (col >> 6) & 15, d = col & 63;
          if (col < DD) {
            Qo[(((size_t)(b * NHH + h)) * LL + l) * HSS + d] = bb;
          } else {
            Ko[(((size_t)(b * NHH + h)) * LL + l) * HSS + d] = bb;
          }
        }
  } else {
    // V region: LDS transpose then coalesced V^T row writes.
    int vb0 = n0 - 2 * DD;            // 128-aligned offset in V cols
    int bq = m0 >> 11, l0 = m0 & 2047;
    int vr = t >> 2, vc = (t & 3) * 8;
#pragma unroll
    for (int c = 0; c < 2; c++) {
      if ((wave & 1) == c) {
#pragma unroll
        for (int mt = 0; mt < 4; mt++)
#pragma unroll
          for (int nt = 0; nt < 4; nt++)
#pragma unroll
            for (int r = 0; r < 4; r++) {
              int vrow = nt * 16 + lr;                 // 0..63 (d within chunk)
              int ml = wm + mt * 16 + qd * 4 + r;      // 0..127 (m within tile)
              Vl[vrow * 136 + ml] = (__bf16)(acc[mt][nt][r] + bvv[nt]);
            }
      }
      __syncthreads();
      int h = (vb0 + c * 64) >> 6;   // chunk is 64-aligned -> single head
      __bf16* dst = Vto + (((size_t)(bq * NHH + h)) * HSS + vr) * LL + l0 + vc;
      const __bf16* src = &Vl[vr * 136 + vc];
#pragma unroll
      for (int u = 0; u < 4; u++)
        *(bf16x8*)(dst + u * 32) = *(const bf16x8*)(src + u * 32);
      __syncthreads();
    }
  }
}

// ---------------------------------------------------------------- GEMM2 (proj)
// out = Y[4096,1024](bf16) @ WprojT^T + bproj.
// R23: single-barrier DMA double-buffer. R25: XCD remap (512%8==0).
// Epilogue = direct writes (R14 staging regressed; 64B/quad is fine).
__global__ __launch_bounds__(256) void gemm_proj_k(
    const __bf16* __restrict__ A, const __bf16* __restrict__ Bt,
    const float* __restrict__ bias, float* __restrict__ out) {
  const int K = 1024, N = 1024;
  __shared__ __align__(16) __bf16 smem[2 * 4096 + 2 * 2048];  // As0|As1|Bs0|Bs1
  int t = threadIdx.x;
  int wave = t >> 6, lane = t & 63, qd = lane >> 4, lr = lane & 15;
  int wg = (int)blockIdx.y * 16 + (int)blockIdx.x;
  wg = (wg & 7) * 64 + (wg >> 3);       // XCD-chunk remap (bijective, 512/8=64)
  int m0 = (wg / 16) * 128, n0 = (wg % 16) * 64;
  int wm = (wave >> 1) * 64, wn = (wave & 1) * 32;
  f32x4 acc[4][2] = {};
  int srow = lane >> 2, sch = (lane & 3) * 8;
  const __bf16* Ab[2];
  const __bf16* Bb;
#pragma unroll
  for (int c = 0; c < 2; c++)
    Ab[c] = A + (size_t)(m0 + (wave * 2 + c) * 16 + srow) * K + sch;
  Bb = Bt + (size_t)(n0 + wave * 16 + srow) * K + sch;

#pragma unroll
  for (int c = 0; c < 2; c++)
    async_ld16(&smem[0 * 4096 + (wave * 2 + c) * 512], Ab[c]);
  async_ld16(&smem[2 * 4096 + wave * 512], Bb);
  __syncthreads();
  int cur = 0;
  for (int k0 = 0; k0 < K; k0 += 32) {
    if (k0 + 32 < K) {
#pragma unroll
      for (int c = 0; c < 2; c++)
        async_ld16(&smem[(cur ^ 1) * 4096 + (wave * 2 + c) * 512], Ab[c] + k0 + 32);
      async_ld16(&smem[2 * 4096 + (cur ^ 1) * 2048 + wave * 512], Bb + k0 + 32);
    }
    const __bf16* As = &smem[cur * 4096];
    const __bf16* Bs = &smem[2 * 4096 + cur * 2048];
    bf16x8 af[4], bfr[2];
#pragma unroll
    for (int mt = 0; mt < 4; mt++)
      af[mt] = *(const bf16x8*)&As[(wm + mt * 16 + lr) * 32 + qd * 8];
#pragma unroll
    for (int nt = 0; nt < 2; nt++)
      bfr[nt] = *(const bf16x8*)&Bs[(wn + nt * 16 + lr) * 32 + qd * 8];
#pragma unroll
    for (int mt = 0; mt < 4; mt++)
#pragma unroll
      for (int nt = 0; nt < 2; nt++)
        acc[mt][nt] = __builtin_amdgcn_mfma_f32_16x16x32_bf16(af[mt], bfr[nt],
                                                              acc[mt][nt], 0, 0, 0);
    __syncthreads();
    cur ^= 1;
  }
  float bvv[2];
#pragma unroll
  for (int nt = 0; nt < 2; nt++) bvv[nt] = bias[n0 + wn + nt * 16 + lr];
#pragma unroll
  for (int mt = 0; mt < 4; mt++)
#pragma unroll
    for (int nt = 0; nt < 2; nt++)
#pragma unroll
      for (int r = 0; r < 4; r++) {
        int row = m0 + wm + mt * 16 + qd * 4 + r;
        int col = n0 + wn + nt * 16 + lr;
        out[(size_t)row * N + col] = acc[mt][nt][r] + bvv[nt];
      }
}

// ---------------------------------------------------------------- flash attn
// SPLIT-K over j (z=2 halves): unnormalized softmax partials are ADDITIVE:
// Y = (O0+O1)/(l0+l1). Grid (bh=32, tile=32 heavy-first, half=2) = 2048.
// Loop = R10 verbatim (106us floor; latency-chain-bound, 7 falsified
// attack angles: occupancy x2, conflicts, staging, barriers, gather
// batching, pipe rebalance, fused combine).
__global__ __launch_bounds__(256, 3) void flash_k(
    const __bf16* __restrict__ Qg, const __bf16* __restrict__ Kg,
    const __bf16* __restrict__ Vtg, const __bf16* __restrict__ Erb,
    __bf16* __restrict__ Po0, __bf16* __restrict__ Po1,
    float* __restrict__ Lp0, float* __restrict__ Lp1) {
  __shared__ __align__(16) __bf16 Kbuf[2][64 * 64];   // [j][d], swizzled
  __shared__ __align__(16) __bf16 Vbuf[2][64 * 64];   // [d][j], swizzled
  __shared__ __align__(16) __bf16 Pball[4][16 * 64];  // per-wave P, swizzled

  int bh = blockIdx.x;
  int tile = 31 - (int)blockIdx.y;  // heavy tiles dispatch first
  int i0 = tile * 64;
  int niter = tile + 1;
  int mid = (niter + 1) >> 1;
  int it0 = (blockIdx.z == 0) ? 0 : mid;
  int it1 = (blockIdx.z == 0) ? mid : niter;
  const __bf16* Qh = Qg + (size_t)bh * LL * HSS;
  const __bf16* Kh = Kg + (size_t)bh * LL * HSS;
  const __bf16* Vth = Vtg + (size_t)bh * HSS * LL;
  int b = bh >> 4, h = bh & 15;
  int t = threadIdx.x, wave = t >> 6, lane = t & 63, qd = lane >> 4, lr = lane & 15;
  __bf16* Pb = &Pball[wave][0];
  int cbase = 48 - wave * 16;

  // 0.125 * log2(e): fold softmax scale + base-e->base-2 into one fp32 mul.
  const float SC = 0.18033688011112042f;

  // DMA source addressing (per-lane, inverse-swizzled):
  int lrow = lane >> 3;                  // 0..7 row within 8-row chunk
  int lcol = ((lane & 7) ^ lrow) * 8;    // swizzled col chunk (elems)
  const __bf16* KsrcB[2];
  const __bf16* VsrcB[2];
#pragma unroll
  for (int c = 0; c < 2; c++) {
    int q = wave * 2 + c;                // chunk 0..7 (8 rows each)
    KsrcB[c] = Kh + (size_t)(q * 8 + lrow) * HSS + lcol;
    VsrcB[c] = Vth + (size_t)(q * 8 + lrow) * LL + lcol;
  }

  // swizzled read col offsets (elems): chunk qd -> qd^(lr&7); qd+4 likewise
  int swA = (qd ^ (lr & 7)) * 8;
  int swB = ((qd + 4) ^ (lr & 7)) * 8;

  // slim per-r invariants (bases only; per-r offsets are unroll constants)
  int hi8 = lr >> 3;
  int ib0 = 15 - qd * 4 + lr;        // bpermute base for r=0
  int pb0 = qd * 256 + (lr & 7);     // P write base (row tr=qd*4+r at +r*64)
  int px0 = (qd & 1) * 4;            // P chunk-xor for r=0
  int rowb = i0 + wave * 16 + qd * 4;  // global row base

  bf16x8 aq[2];
  {
    const __bf16* qrow = Qh + (size_t)(i0 + wave * 16 + lr) * HSS + qd * 8;
    aq[0] = *(const bf16x8*)qrow;
    aq[1] = *(const bf16x8*)(qrow + 32);
  }
  f32x4 oacc[4] = {};   // O d-tiles
  float lsum[4] = {};   // row sums (VALU)

  // prologue: DMA tile it0 into buffer 0, then barrier (drains vmcnt).
  int cur = 0;
  if (it0 < it1) {
    int j0 = it0 * 64;
#pragma unroll
    for (int c = 0; c < 2; c++) {
      async_ld16(&Kbuf[0][(wave * 2 + c) * 512], KsrcB[c] + (size_t)j0 * HSS);
      async_ld16(&Vbuf[0][(wave * 2 + c) * 512], VsrcB[c] + j0);
    }
  }
  __syncthreads();

  for (int it = it0; it < it1; ++it) {
    int j0 = it * 64;

    // issue DMA for NEXT tile into the other buffer; completes before the
    // trailing barrier's vmcnt drain (a full iteration of compute away).
    if (it + 1 < it1) {
      int jn = (it + 1) * 64;
#pragma unroll
      for (int c = 0; c < 2; c++) {
        async_ld16(&Kbuf[cur ^ 1][(wave * 2 + c) * 512], KsrcB[c] + (size_t)jn * HSS);
        async_ld16(&Vbuf[cur ^ 1][(wave * 2 + c) * 512], VsrcB[c] + jn);
      }
    }

    // Er rows for this iter's 80-col window (clamped rows feed masked cols).
    int ebase = LL - 64 - i0 + j0 + cbase + lr;
    int e[5];
#pragma unroll
    for (int ct = 0; ct < 5; ct++) {
      int v = ebase + ct * 16;
      e[ct] = (v < LL) ? v : (LL - 1);
    }
    // kc=0 Er batch issued BEFORE QK: QK MFMAs + ds_reads hide L2 latency.
    bf16x8 ef0[5];
#pragma unroll
    for (int ct = 0; ct < 5; ct++)
      ef0[ct] = *(const bf16x8*)&Erb[(size_t)e[ct] * HSS + qd * 8];

    const __bf16* Kb = &Kbuf[cur][0];
    const __bf16* Vb = &Vbuf[cur][0];

    // QK^T: 4 col-tiles x 2 k-chunks (swizzled LDS reads)
    f32x4 sacc[4] = {};
    __builtin_amdgcn_s_setprio(1);
#pragma unroll
    for (int ct = 0; ct < 4; ct++) {
      bf16x8 bk0 = *(const bf16x8*)&Kb[(ct * 16 + lr) * 64 + swA];
      bf16x8 bk1 = *(const bf16x8*)&Kb[(ct * 16 + lr) * 64 + swB];
      sacc[ct] = __builtin_amdgcn_mfma_f32_16x16x32_bf16(aq[0], bk0, sacc[ct], 0, 0, 0);
      sacc[ct] = __builtin_amdgcn_mfma_f32_16x16x32_bf16(aq[1], bk1, sacc[ct], 0, 0, 0);
    }
    __builtin_amdgcn_s_setprio(0);

    // kc=1 Er batch issued here, consumed after the kc=0 rel MFMAs.
    bf16x8 ef1[5];
#pragma unroll
    for (int ct = 0; ct < 5; ct++)
      ef1[ct] = *(const bf16x8*)&Erb[(size_t)e[ct] * HSS + 32 + qd * 8];

    // rel: 5 col-tiles over the 80-col window, B-frags from registers
    f32x4 racc[5] = {};
    __builtin_amdgcn_s_setprio(1);
#pragma unroll
    for (int ct = 0; ct < 5; ct++)
      racc[ct] = __builtin_amdgcn_mfma_f32_16x16x32_bf16(aq[0], ef0[ct], racc[ct], 0, 0, 0);
#pragma unroll
    for (int ct = 0; ct < 5; ct++)
      racc[ct] = __builtin_amdgcn_mfma_f32_16x16x32_bf16(aq[1], ef1[ct], racc[ct], 0, 0, 0);
    __builtin_amdgcn_s_setprio(0);

    // Rel diagonal gather via bpermute, p = exp2(SC*s), l on VALU.
    int dib = rowb - j0;
#pragma unroll
    for (int r = 0; r < 4; r++) {
      int bse = ib0 - r;
      int hi = bse >> 4;
      int idx = (qd * 16 + (bse & 15)) << 2;
      float sh[5];
#pragma unroll
      for (int ct = 0; ct < 5; ct++)
        sh[ct] = __int_as_float(
            __builtin_amdgcn_ds_bpermute(idx, __float_as_int(racc[ct][r])));
      int di = dib + r;
#pragma unroll
      for (int ct2 = 0; ct2 < 4; ct2++) {
        float rel = hi ? sh[ct2 + 1] : sh[ct2];
        float p = __builtin_exp2f((sacc[ct2][r] + rel) * SC);
        p = (ct2 * 16 + lr <= di) ? p : 0.f;
        __bf16 pb = (__bf16)p;
        lsum[r] += (float)pb;  // bf16-rounded to match PV numerics
        Pb[pb0 + r * 64 + (((2 * ct2 + hi8) ^ (px0 + r)) << 3)] = pb;
      }
    }

    // O += P V (dt 0..3, swizzled LDS V-frags; P read swizzled like K/V)
    bf16x8 ap0 = *(const bf16x8*)&Pb[lr * 64 + swA];
    bf16x8 ap1 = *(const bf16x8*)&Pb[lr * 64 + swB];
    __builtin_amdgcn_s_setprio(1);
#pragma unroll
    for (int dt = 0; dt < 4; dt++) {
      bf16x8 bv0 = *(const bf16x8*)&Vb[(dt * 16 + lr) * 64 + swA];
      bf16x8 bv1 = *(const bf16x8*)&Vb[(dt * 16 + lr) * 64 + swB];
      oacc[dt] = __builtin_amdgcn_mfma_f32_16x16x32_bf16(ap0, bv0, oacc[dt], 0, 0, 0);
      oacc[dt] = __builtin_amdgcn_mfma_f32_16x16x32_bf16(ap1, bv1, oacc[dt], 0, 0, 0);
    }
    __builtin_amdgcn_s_setprio(0);

    __syncthreads();  // next buffer ready (vmcnt drained), P safe to rewrite
    cur ^= 1;
  }

  // l: reduce across the 16 lanes of each quad-group (cols of the row).
#pragma unroll
  for (int r = 0; r < 4; r++) {
#pragma unroll
    for (int m = 1; m < 16; m <<= 1)
      lsum[r] += __shfl_xor(lsum[r], m, 64);
  }

  // epilogue: write UNNORMALIZED partial O (bf16) and partial l (fp32).
  __bf16* Po = (blockIdx.z == 0) ? Po0 : Po1;
  float* Lp = (blockIdx.z == 0) ? Lp0 : Lp1;
#pragma unroll
  for (int r = 0; r < 4; r++) {
    int l = i0 + wave * 16 + qd * 4 + r;
    if (lr == 0) Lp[(size_t)bh * LL + l] = lsum[r];
#pragma unroll
    for (int dt = 0; dt < 4; dt++) {
      int d = dt * 16 + lr;
      Po[((size_t)(b * LL) + l) * DD + h * HSS + d] = (__bf16)oacc[dt][r];
    }
  }
}

// ------------------------------------------------- combine + tconv (fused)
// id < 2048:  Y = (Po0 + Po1) / (Lp0 + Lp1)  elementwise (256 thr/blk x8).
// id >= 2048: Wproj fp32 [1024][1024] -> WprojT bf16 (32x32 tiles, 1024 blk).
__global__ void ct_k(const __bf16* __restrict__ Po0,
                     const __bf16* __restrict__ Po1,
                     const float* __restrict__ Lp0,
                     const float* __restrict__ Lp1,
                     __bf16* __restrict__ Y,
                     const float* __restrict__ Wproj,
                     __bf16* __restrict__ WprojT) {
  int id = blockIdx.x;
  if (id < 2048) {
    size_t f = ((size_t)id * 256 + threadIdx.x) * 8;
    int dfull = (int)(f & 1023);
    int h = dfull >> 6;
    int l = (int)((f >> 10) & 2047);
    int b = (int)(f >> 21);
    size_t lidx = ((size_t)(b * NHH + h)) * LL + l;
    float linv = 1.f / (Lp0[lidx] + Lp1[lidx]);
    bf16x8 a = *(const bf16x8*)&Po0[f];
    bf16x8 c = *(const bf16x8*)&Po1[f];
    bf16x8 o;
#pragma unroll
    for (int q = 0; q < 8; q++)
      o[q] = (__bf16)(((float)a[q] + (float)c[q]) * linv);
    *(bf16x8*)&Y[f] = o;
    return;
  }
  __shared__ __bf16 tile[32][33];
  int q = id - 2048;
  int c0 = (q & 31) * 32, r0 = (q >> 5) * 32;
  int tx = threadIdx.x & 31, ty = threadIdx.x >> 5;
#pragma unroll
  for (int i = ty; i < 32; i += 8)
    tile[i][tx] = (__bf16)Wproj[(size_t)(r0 + i) * 1024 + c0 + tx];
  __syncthreads();
#pragma unroll
  for (int i = ty; i < 32; i += 8)
    WprojT[(size_t)(c0 + i) * 1024 + r0 + tx] = tile[tx][i];
}

// ---------------------------------------------------------------- launch
extern "C" void kernel_launch(void* const* d_in, const int* in_sizes, int n_in,
                              void* d_out, int out_size, void* d_ws, size_t ws_size,
                              hipStream_t stream) {
  // Reference dtypes: ALL inputs fp32, output fp32 (confirmed round 4).
  const float* x = (const float*)d_in[0];
  const float* Wqkv = (const float*)d_in[1];
  const float* bqkv = (const float*)d_in[2];
  const float* Wproj = (const float*)d_in[3];
  const float* bproj = (const float*)d_in[4];
  const float* Er = (const float*)d_in[5];
  float* out = (float*)d_out;

  if (ws_size < 4u * 8388608u) return;  // 32 MiB used, confirmed present

  uint8_t* w = (uint8_t*)d_ws;
  __bf16* Q = (__bf16*)w;  w += (size_t)BB * NHH * LL * HSS * 2;
  __bf16* Kt = (__bf16*)w; w += (size_t)BB * NHH * LL * HSS * 2;
  __bf16* Vt = (__bf16*)w; w += (size_t)BB * NHH * LL * HSS * 2;
  __bf16* Y = (__bf16*)w;  w += (size_t)BB * LL * DD * 2;

  // d_out scratch overlay (16.78 MB):
  //   Pre-GEMM1: WqkvT 6.29 MB @0, xb 8.39 MB @6.29M (both dead after GEMM1).
  //   During flash: Po1 8.39 MB @0, Lp0 0.26 MB @8.39M, Lp1 0.26 MB @8.65M,
  //   Erb 0.26 MB @14.68M (live through flash; no overlap).
  //   gemm_proj overwrites all of d_out last.
  __bf16* WqkvT = (__bf16*)d_out;
  __bf16* xb = (__bf16*)((uint8_t*)d_out + (size_t)3072 * 1024 * 2);
  __bf16* Erb = (__bf16*)((uint8_t*)d_out + (size_t)3072 * 1024 * 2 + (size_t)4096 * 1024 * 2);
  __bf16* Po1 = (__bf16*)d_out;
  float* Lp0 = (float*)((uint8_t*)d_out + (size_t)BB * LL * DD * 2);
  float* Lp1 = (float*)((uint8_t*)d_out + (size_t)BB * LL * DD * 2 + (size_t)BB * NHH * LL * 4);
  __bf16* Po0 = Y;       // ct_k reads+rewrites Y in place (same-thread RAW)
  __bf16* WprojT = Q;    // written after flash (Q dead by then)

  prep_k<<<dim3(3072, 1, 3), dim3(32, 8), 0, stream>>>(Wqkv, x, Er, WqkvT, xb, Erb);
  gemm_qkv_k<<<dim3(3072 / 128, 4096 / 128), 256, 0, stream>>>(
      xb, WqkvT, bqkv, Q, Kt, Vt);
  flash_k<<<dim3(BB * NHH, 32, 2), 256, 0, stream>>>(
      Q, Kt, Vt, Erb, Po0, Po1, Lp0, Lp1);
  ct_k<<<dim3(3072), 256, 0, stream>>>(Po0, Po1, Lp0, Lp1, Y, Wproj, WprojT);
  gemm_proj_k<<<dim3(1024 / 64, 4096 / 128), 256, 0, stream>>>(Y, WprojT, bproj, out);
}